// Round 12
// baseline (458.702 us; speedup 1.0000x reference)
//
#include <hip/hip_runtime.h>
#include <hip/hip_bf16.h>

typedef __attribute__((ext_vector_type(8))) short short8;
typedef __attribute__((ext_vector_type(4))) float floatx4;
typedef __attribute__((ext_vector_type(16))) float floatx16;

__device__ __forceinline__ unsigned short f2bf(float x) {
  __hip_bfloat16 h = __float2bfloat16(x);
  return __builtin_bit_cast(unsigned short, h);
}

// ---------------------------------------------------------------------
// X (fp32) -> bf16 copy
// ---------------------------------------------------------------------
__global__ __launch_bounds__(256) void cvt_x_kernel(
    const float* __restrict__ X, unsigned short* __restrict__ Xbf, int n) {
  int i = blockIdx.x * 256 + threadIdx.x;
  if (i < n) Xbf[i] = f2bf(X[i]);
}

// ---------------------------------------------------------------------
// Build extended transposed weights: Bt[o][r], r = k*64+d for k<K2 (from
// W[k][d][o]), and r in [K2*64, K2*64+64) from root[d][o]. bf16.
// ---------------------------------------------------------------------
__global__ __launch_bounds__(256) void cvt_wext_kernel(
    const float* __restrict__ W, const float* __restrict__ root,
    unsigned short* __restrict__ Bt, int K2) {
  int R = (K2 + 1) * 64;
  int i = blockIdx.x * 256 + threadIdx.x;
  if (i >= 64 * R) return;
  int o = i / R, r = i - o * R;
  int k = r >> 6, d = r & 63;
  float v = (k < K2) ? W[(k << 12) + (d << 6) + o] : root[(d << 6) + o];
  Bt[(size_t)o * R + r] = f2bf(v);
}

// ---------------------------------------------------------------------
// CSR build: histogram -> scan -> cursor scatter
// ---------------------------------------------------------------------
__global__ __launch_bounds__(256) void zero_int_kernel(int* __restrict__ p, int n) {
  int i = blockIdx.x * 256 + threadIdx.x;
  if (i < n) p[i] = 0;
}

__global__ __launch_bounds__(256) void hist_kernel(
    const int* __restrict__ dst, int* __restrict__ deg, int nE) {
  int e = blockIdx.x * 256 + threadIdx.x;
  if (e < nE) atomicAdd(&deg[dst[e]], 1);
}

__global__ __launch_bounds__(256) void blocksum_kernel(
    const int* __restrict__ deg, int* __restrict__ partial, int N) {
  __shared__ int s[256];
  int t = threadIdx.x, i = blockIdx.x * 256 + t;
  s[t] = (i < N) ? deg[i] : 0;
  __syncthreads();
  for (int off = 128; off > 0; off >>= 1) {
    if (t < off) s[t] += s[t + off];
    __syncthreads();
  }
  if (t == 0) partial[blockIdx.x] = s[0];
}

__global__ __launch_bounds__(256) void scanpartials_kernel(
    int* __restrict__ partial, int nb) {
  __shared__ int s[256];
  int t = threadIdx.x;
  int v = (t < nb) ? partial[t] : 0;
  s[t] = v;
  __syncthreads();
  for (int off = 1; off < 256; off <<= 1) {
    int x = (t >= off) ? s[t - off] : 0;
    __syncthreads();
    s[t] += x;
    __syncthreads();
  }
  if (t < nb) partial[t] = s[t] - v;
}

__global__ __launch_bounds__(256) void blockscan_kernel(
    const int* __restrict__ deg, const int* __restrict__ partial,
    int* __restrict__ row_start, int* __restrict__ cursor, int N, int nE) {
  __shared__ int s[256];
  int t = threadIdx.x, i = blockIdx.x * 256 + t;
  int v = (i < N) ? deg[i] : 0;
  s[t] = v;
  __syncthreads();
  for (int off = 1; off < 256; off <<= 1) {
    int x = (t >= off) ? s[t - off] : 0;
    __syncthreads();
    s[t] += x;
    __syncthreads();
  }
  if (i < N) {
    int excl = s[t] - v + partial[blockIdx.x];
    row_start[i] = excl;
    cursor[i] = excl;
  }
  if (i == 0) row_start[N] = nE;
}

__global__ __launch_bounds__(256) void scatter_kernel(
    const int* __restrict__ dst, int* __restrict__ cursor,
    int* __restrict__ eidx, int nE) {
  int e = blockIdx.x * 256 + threadIdx.x;
  if (e < nE) {
    int pos = atomicAdd(&cursor[dst[e]], 1);
    eidx[pos] = e;
  }
}

// ---------------------------------------------------------------------
// Z-build via MFMA: one wave per dst node. Per 16-edge chunk:
//   D[bucket][ch] += A[bucket][edge] * B[edge][ch]     (32x32x16 bf16 MFMA x2)
// Z is written with NON-TEMPORAL stores: the 166 MB stream otherwise
// write-allocates through L2/L3 and evicts the hot 20 MB gather set
// (R10 counters: FETCH=169 MB vs ~20 MB working set).
// Z layout: [N x K2*64] (root row dropped; GEMM reads it from Xbf direct).
// ---------------------------------------------------------------------
template <int K, int K2>
__global__ __launch_bounds__(256) void zbuild_kernel(
    const int* __restrict__ eidx, const int* __restrict__ row_start,
    const int* __restrict__ src, const float* __restrict__ attr,
    const unsigned short* __restrict__ Xbf, unsigned short* __restrict__ Z,
    int N) {
  constexpr int R = K2 * 64;
  __shared__ float4 sMeta[4][16];    // per wave: f0, f1, l0|l1<<8, elem-offset
  const int t = threadIdx.x, w = t >> 6, lane = t & 63;
  const int node = blockIdx.x * 4 + w;
  if (node >= N) return;   // wave-uniform; no __syncthreads in this kernel

  const int col = lane & 31;     // A: bucket row m  /  B: channel col n
  const int half = lane >> 5;    // k-half
  const int mi0 = (col < K2) ? (col % K) : -3;
  const int mi1 = (col < K2) ? (col / K) : -3;

  floatx16 d0, d1;
#pragma unroll
  for (int i = 0; i < 16; ++i) { d0[i] = 0.f; d1[i] = 0.f; }

  const int beg = row_start[node], end = row_start[node + 1];
  for (int c0 = beg; c0 < end; c0 += 16) {
    const int m = min(16, end - c0);
    if (lane < 16) {
      float f0 = 0.f, f1 = 0.f;
      int lpack = 0x7F7F, off = 0;
      if (lane < m) {
        int e = eidx[c0 + lane];
        float2 a = *(const float2*)&attr[2 * e];
        int s = src[e];
        float u = a.x * (float)(K - 1);
        float v = a.y * (float)(K - 1);
        int l0 = min((int)u, K - 2);   // exact clip-equivalent for u in [0,K-1)
        int l1 = min((int)v, K - 2);
        f0 = u - (float)l0;
        f1 = v - (float)l1;
        lpack = l0 | (l1 << 8);
        off = s * 64;
      }
      sMeta[w][lane] = make_float4(f0, f1, __builtin_bit_cast(float, lpack),
                                   __builtin_bit_cast(float, off));
    }
    // same-wave LDS write->read (lockstep; compiler inserts lgkmcnt)
    short8 A, Blo, Bhi;
#pragma unroll
    for (int j = 0; j < 8; ++j) {
      float4 md = sMeta[w][half * 8 + j];
      int lp = __builtin_bit_cast(int, md.z);
      int off = __builtin_bit_cast(int, md.w);
      int l0 = lp & 0xFF, l1 = (lp >> 8) & 0xFF;
      float su = (mi0 == l0) ? (1.f - md.x) : ((mi0 == l0 + 1) ? md.x : 0.f);
      float sv = (mi1 == l1) ? (1.f - md.y) : ((mi1 == l1 + 1) ? md.y : 0.f);
      A[j] = (short)f2bf(su * sv);
      Blo[j] = (short)Xbf[off + col];
      Bhi[j] = (short)Xbf[off + 32 + col];
    }
    d0 = __builtin_amdgcn_mfma_f32_32x32x16_bf16(A, Blo, d0, 0, 0, 0);
    d1 = __builtin_amdgcn_mfma_f32_32x32x16_bf16(A, Bhi, d1, 0, 0, 0);
  }

  const int deg = end - beg;
  const float inv = 1.f / (float)max(deg, 1);
  unsigned short* zr = Z + (size_t)node * R;
#pragma unroll
  for (int reg = 0; reg < 16; ++reg) {
    int r = (reg & 3) + 8 * (reg >> 2) + 4 * half;
    if (r < K2) {
      __builtin_nontemporal_store(f2bf(d0[reg] * inv), &zr[r * 64 + col]);
      __builtin_nontemporal_store(f2bf(d1[reg] * inv), &zr[r * 64 + 32 + col]);
    }
  }
}

// ---------------------------------------------------------------------
// Fused GEMM: out[n,o] = ELU( [Z[n,:] | Xr[n,:]] @ Bt[o,:] + bias[o] )
// Z chunks kc<KC-1 read NON-TEMPORAL (streaming, ext-vector floatx4);
// last chunk (root row) from cache-hot Xr. OUTBF=1 -> bf16 out, else fp32.
// ---------------------------------------------------------------------
template <int KC, int OUTBF>
__global__ __launch_bounds__(256) void gemm_fused_kernel(
    const unsigned short* __restrict__ Z, const unsigned short* __restrict__ Bt,
    const unsigned short* __restrict__ Xr, const float* __restrict__ bias,
    void* __restrict__ outv, int N) {
  constexpr int RZ = (KC - 1) * 64;
  constexpr int R = KC * 64;
  __shared__ unsigned short As[64 * 72];
  __shared__ unsigned short Bs[64 * 72];
  const int t = threadIdx.x, w = t >> 6, lane = t & 63;
  const int mrow = lane & 15, q = lane >> 4;
  const int n0 = blockIdx.x * 64;

  floatx4 acc[4] = {{0,0,0,0},{0,0,0,0},{0,0,0,0},{0,0,0,0}};

  for (int kc = 0; kc < KC; ++kc) {
    __syncthreads();
    for (int i = t; i < 512; i += 256) {
      int row = i >> 3, cg = i & 7;
      int n = n0 + row;
      floatx4 val = {0.f, 0.f, 0.f, 0.f};
      if (n < N) {
        if (kc < KC - 1)
          val = __builtin_nontemporal_load(
              (const floatx4*)&Z[(size_t)n * RZ + kc * 64 + cg * 8]);
        else
          val = *(const floatx4*)&Xr[(size_t)n * 64 + cg * 8];
      }
      *(floatx4*)&As[row * 72 + cg * 8] = val;
    }
    for (int i = t; i < 512; i += 256) {
      int row = i >> 3, cg = i & 7;
      *(floatx4*)&Bs[row * 72 + cg * 8] =
          *(const floatx4*)&Bt[(size_t)row * R + kc * 64 + cg * 8];
    }
    __syncthreads();

    short8 a0 = *(const short8*)&As[(w * 16 + mrow) * 72 + q * 8];
    short8 a1 = *(const short8*)&As[(w * 16 + mrow) * 72 + 32 + q * 8];
#pragma unroll
    for (int ot = 0; ot < 4; ++ot) {
      short8 b0 = *(const short8*)&Bs[(ot * 16 + mrow) * 72 + q * 8];
      short8 b1 = *(const short8*)&Bs[(ot * 16 + mrow) * 72 + 32 + q * 8];
      acc[ot] = __builtin_amdgcn_mfma_f32_16x16x32_bf16(a0, b0, acc[ot], 0, 0, 0);
      acc[ot] = __builtin_amdgcn_mfma_f32_16x16x32_bf16(a1, b1, acc[ot], 0, 0, 0);
    }
  }

  // epilogue: D layout col(o)=ot*16+mrow, row(node)=q*4+r
#pragma unroll
  for (int ot = 0; ot < 4; ++ot) {
    float b = bias[ot * 16 + mrow];
#pragma unroll
    for (int r = 0; r < 4; ++r) {
      int node = n0 + w * 16 + q * 4 + r;
      if (node < N) {
        float v = acc[ot][r] + b;
        v = v > 0.f ? v : (expf(v) - 1.f);
        if (OUTBF)
          ((unsigned short*)outv)[(size_t)node * 64 + ot * 16 + mrow] = f2bf(v);
        else
          ((float*)outv)[(size_t)node * 64 + ot * 16 + mrow] = v;
      }
    }
  }
}

// ---------------------------------------------------------------------
// dense layer (fp32 VALU): out = act(X@Wm + b); ACT 1=ReLU
// ---------------------------------------------------------------------
template <int ACT>
__global__ __launch_bounds__(256) void node_dense_kernel(
    const float* __restrict__ X, const float* __restrict__ Wm,
    const float* __restrict__ bias, float* __restrict__ out, int N) {
  __shared__ float Ws[64 * 64];
  __shared__ float XsT[64 * 132];
  const int t = threadIdx.x;
  const int n0 = blockIdx.x * 128;

  for (int i = t; i < 1024; i += 256)
    ((float4*)Ws)[i] = ((const float4*)Wm)[i];
  for (int i = t; i < 8192; i += 256) {
    int nl = i >> 6, d = i & 63;
    int n = n0 + nl;
    XsT[d * 132 + nl] = (n < N) ? X[(size_t)n * 64 + d] : 0.f;
  }
  __syncthreads();

  const int o = t & 63, ng = t >> 6;
  float acc[32];
#pragma unroll
  for (int j = 0; j < 32; ++j) acc[j] = 0.f;

  for (int d = 0; d < 64; ++d) {
    float w = Ws[d * 64 + o];
    const float4* xp = (const float4*)&XsT[d * 132 + ng * 32];
#pragma unroll
    for (int j4 = 0; j4 < 8; ++j4) {
      float4 xv = xp[j4];
      acc[j4 * 4 + 0] += xv.x * w;
      acc[j4 * 4 + 1] += xv.y * w;
      acc[j4 * 4 + 2] += xv.z * w;
      acc[j4 * 4 + 3] += xv.w * w;
    }
  }

  float b = bias[o];
#pragma unroll
  for (int j = 0; j < 32; ++j) {
    int n = n0 + ng * 32 + j;
    if (n >= N) continue;
    float v = acc[j] + b;
    if (ACT == 0) v = v > 0.f ? v : (expf(v) - 1.f);
    else          v = v > 0.f ? v : 0.f;
    out[(size_t)n * 64 + o] = v;
  }
}

// ---------------------------------------------------------------------
// final projection D=64 -> C=8 with ReLU
// ---------------------------------------------------------------------
__global__ __launch_bounds__(256) void mlp2_kernel(
    const float* __restrict__ X, const float* __restrict__ W,
    const float* __restrict__ bias, float* __restrict__ out, int N) {
  __shared__ float Ws[512];
  __shared__ float bs[8];
  __shared__ float Xs[32 * 64];
  int t = threadIdx.x;
  int n0 = blockIdx.x * 32;
  if (t < 8) bs[t] = bias[t];
  for (int i = t; i < 512; i += 256) Ws[i] = W[i];
  for (int i = t; i < 512; i += 256) {
    int n = n0 + (i >> 4);
    ((float4*)Xs)[i] = (n < N) ? ((const float4*)(X + (size_t)n * 64))[i & 15]
                               : make_float4(0.f, 0.f, 0.f, 0.f);
  }
  __syncthreads();
  int c = t & 7, nl = t >> 3;
  float acc = bs[c];
  for (int d = 0; d < 64; ++d) acc += Xs[nl * 64 + d] * Ws[d * 8 + c];
  int n = n0 + nl;
  if (n < N) out[(size_t)n * 8 + c] = acc > 0.f ? acc : 0.f;
}

// ---------------------------------------------------------------------
extern "C" void kernel_launch(void* const* d_in, const int* in_sizes, int n_in,
                              void* d_out, int out_size, void* d_ws, size_t ws_size,
                              hipStream_t stream) {
  const float* x     = (const float*)d_in[0];
  const int*   ei    = (const int*)d_in[1];
  const float* attr  = (const float*)d_in[2];
  const float* W1    = (const float*)d_in[3];
  const float* root1 = (const float*)d_in[4];
  const float* b1    = (const float*)d_in[5];
  const float* W2    = (const float*)d_in[6];
  const float* root2 = (const float*)d_in[7];
  const float* b2    = (const float*)d_in[8];
  const float* m1w   = (const float*)d_in[9];
  const float* m1b   = (const float*)d_in[10];
  const float* m2w   = (const float*)d_in[11];
  const float* m2b   = (const float*)d_in[12];

  const int N  = in_sizes[0] / 64;
  const int nE = in_sizes[1] / 2;
  const int* src  = ei;
  const int* dstv = ei + nE;
  float* out = (float*)d_out;

  // workspace layout
  float* h2 = (float*)d_ws;                 // N*64 fp32
  float* t1 = h2 + (size_t)N * 64;          // N*64 fp32
  int* deg       = (int*)(t1 + (size_t)N * 64);
  int* row_start = deg + N;
  int* cursor    = row_start + (N + 1);
  int* eidx      = cursor + N;
  int* partial   = eidx + nE;               // 256
  char* pbase = (char*)(partial + 256);
  pbase = (char*)(((uintptr_t)pbase + 15) & ~(uintptr_t)15);
  unsigned short* Xbf  = (unsigned short*)pbase;      // N*64 bf16
  unsigned short* h1bf = Xbf + (size_t)N * 64;        // N*64 bf16
  unsigned short* Bt1  = h1bf + (size_t)N * 64;       // 64 * 640
  unsigned short* Bt2  = Bt1 + 64 * 640;              // 64 * 1664
  unsigned short* Z    = Bt2 + 64 * 1664;             // N * 1600

  dim3 blk(256);
  int nbN  = (N + 255) / 256;
  int nbE  = (nE + 255) / 256;
  int nbZ  = (N + 3) / 4;
  int nbG  = (N + 63) / 64;
  int nb128 = (N + 127) / 128;

  // ----- CSR build (graph identical both layers) -----
  zero_int_kernel<<<nbN, blk, 0, stream>>>(deg, N);
  hist_kernel<<<nbE, blk, 0, stream>>>(dstv, deg, nE);
  blocksum_kernel<<<nbN, blk, 0, stream>>>(deg, partial, N);
  scanpartials_kernel<<<1, blk, 0, stream>>>(partial, nbN);
  blockscan_kernel<<<nbN, blk, 0, stream>>>(deg, partial, row_start, cursor, N, nE);
  scatter_kernel<<<nbE, blk, 0, stream>>>(dstv, cursor, eidx, nE);

  // ----- weight / input prep -----
  cvt_wext_kernel<<<(64 * 640 + 255) / 256, blk, 0, stream>>>(W1, root1, Bt1, 9);
  cvt_wext_kernel<<<(64 * 1664 + 255) / 256, blk, 0, stream>>>(W2, root2, Bt2, 25);
  cvt_x_kernel<<<(N * 64 + 255) / 256, blk, 0, stream>>>(x, Xbf, N * 64);

  // ----- layer 1 (K=3, K2=9) -----
  zbuild_kernel<3, 9><<<nbZ, blk, 0, stream>>>(eidx, row_start, src, attr, Xbf, Z, N);
  gemm_fused_kernel<10, 1><<<nbG, blk, 0, stream>>>(Z, Bt1, Xbf, b1, h1bf, N);

  // ----- layer 2 (K=5, K2=25) -----
  zbuild_kernel<5, 25><<<nbZ, blk, 0, stream>>>(eidx, row_start, src, attr, h1bf, Z, N);
  gemm_fused_kernel<26, 0><<<nbG, blk, 0, stream>>>(Z, Bt2, h1bf, b2, h2, N);

  // ----- MLP head -----
  node_dense_kernel<1><<<nb128, blk, 0, stream>>>(h2, m1w, m1b, t1, N);
  mlp2_kernel<<<(N + 31) / 32, blk, 0, stream>>>(t1, m2w, m2b, out, N);
}

// Round 13
// 418.134 us; speedup vs baseline: 1.0970x; 1.0970x over previous
//
#include <hip/hip_runtime.h>
#include <hip/hip_bf16.h>

typedef __attribute__((ext_vector_type(8))) short short8;
typedef __attribute__((ext_vector_type(4))) float floatx4;
typedef __attribute__((ext_vector_type(16))) float floatx16;

__device__ __forceinline__ unsigned short f2bf(float x) {
  __hip_bfloat16 h = __float2bfloat16(x);
  return __builtin_bit_cast(unsigned short, h);
}

// ---------------------------------------------------------------------
// X (fp32) -> bf16 copy
// ---------------------------------------------------------------------
__global__ __launch_bounds__(256) void cvt_x_kernel(
    const float* __restrict__ X, unsigned short* __restrict__ Xbf, int n) {
  int i = blockIdx.x * 256 + threadIdx.x;
  if (i < n) Xbf[i] = f2bf(X[i]);
}

// ---------------------------------------------------------------------
// Pack extended weights [W | root] into MFMA B-fragment order:
// Bpk[(((kc*4)+wv)*64 + lane)*8 + j] = Wext[wv*16 + (lane&15)]
//                                          [kc*32 + ((lane>>4)&3)*8 + j]
// where Wext[o][r] = W[k][d][o] (r=k*64+d, k<K2) else root[d][o].
// Phase-2 wave w then loads its B fragment as ONE coalesced 16B/lane read.
// ---------------------------------------------------------------------
__global__ __launch_bounds__(256) void pack_b_kernel(
    const float* __restrict__ W, const float* __restrict__ root,
    unsigned short* __restrict__ Bpk, int K2) {
  int R = (K2 + 1) * 64;
  int total = 64 * R;
  int i = blockIdx.x * 256 + threadIdx.x;
  if (i >= total) return;
  int j = i & 7;
  int lane = (i >> 3) & 63;
  int rest = i >> 9;            // kc*4 + wv
  int wv = rest & 3, kc = rest >> 2;
  int o = wv * 16 + (lane & 15);
  int r = kc * 32 + ((lane >> 4) & 3) * 8 + j;
  int k = r >> 6, d = r & 63;
  float v = (k < K2) ? W[(k << 12) + (d << 6) + o] : root[(d << 6) + o];
  Bpk[i] = f2bf(v);
}

// ---------------------------------------------------------------------
// CSR build: histogram -> scan -> cursor scatter
// ---------------------------------------------------------------------
__global__ __launch_bounds__(256) void zero_int_kernel(int* __restrict__ p, int n) {
  int i = blockIdx.x * 256 + threadIdx.x;
  if (i < n) p[i] = 0;
}

__global__ __launch_bounds__(256) void hist_kernel(
    const int* __restrict__ dst, int* __restrict__ deg, int nE) {
  int e = blockIdx.x * 256 + threadIdx.x;
  if (e < nE) atomicAdd(&deg[dst[e]], 1);
}

__global__ __launch_bounds__(256) void blocksum_kernel(
    const int* __restrict__ deg, int* __restrict__ partial, int N) {
  __shared__ int s[256];
  int t = threadIdx.x, i = blockIdx.x * 256 + t;
  s[t] = (i < N) ? deg[i] : 0;
  __syncthreads();
  for (int off = 128; off > 0; off >>= 1) {
    if (t < off) s[t] += s[t + off];
    __syncthreads();
  }
  if (t == 0) partial[blockIdx.x] = s[0];
}

__global__ __launch_bounds__(256) void scanpartials_kernel(
    int* __restrict__ partial, int nb) {
  __shared__ int s[256];
  int t = threadIdx.x;
  int v = (t < nb) ? partial[t] : 0;
  s[t] = v;
  __syncthreads();
  for (int off = 1; off < 256; off <<= 1) {
    int x = (t >= off) ? s[t - off] : 0;
    __syncthreads();
    s[t] += x;
    __syncthreads();
  }
  if (t < nb) partial[t] = s[t] - v;
}

__global__ __launch_bounds__(256) void blockscan_kernel(
    const int* __restrict__ deg, const int* __restrict__ partial,
    int* __restrict__ row_start, int* __restrict__ cursor, int N, int nE) {
  __shared__ int s[256];
  int t = threadIdx.x, i = blockIdx.x * 256 + t;
  int v = (i < N) ? deg[i] : 0;
  s[t] = v;
  __syncthreads();
  for (int off = 1; off < 256; off <<= 1) {
    int x = (t >= off) ? s[t - off] : 0;
    __syncthreads();
    s[t] += x;
    __syncthreads();
  }
  if (i < N) {
    int excl = s[t] - v + partial[blockIdx.x];
    row_start[i] = excl;
    cursor[i] = excl;
  }
  if (i == 0) row_start[N] = nE;
}

__global__ __launch_bounds__(256) void scatter_kernel(
    const int* __restrict__ dst, int* __restrict__ cursor,
    int* __restrict__ eidx, int nE) {
  int e = blockIdx.x * 256 + threadIdx.x;
  if (e < nE) {
    int pos = atomicAdd(&cursor[dst[e]], 1);
    eidx[pos] = e;
  }
}

// ---------------------------------------------------------------------
// FUSED spline layer: block = 4 waves = 16 dst nodes.
// Phase 1 (per wave, 4 nodes): MFMA bucket-aggregate (32x32x16) exactly as
//   the standalone zbuild, then write scaled Z row + root row into LDS.
// Phase 2 (block GEMM): out[16 x 64] = ELU( A[16 x R] @ Bt[R x 64] + b ),
//   A from LDS, B from pre-packed Bpk (one 16B/lane coalesced load / MFMA).
// Z never touches HBM -> no 160MB write+read, L3 stays hot for gathers.
// ---------------------------------------------------------------------
template <int K, int K2, int OUTBF>
__global__ __launch_bounds__(256) void spline_layer_kernel(
    const int* __restrict__ eidx, const int* __restrict__ row_start,
    const int* __restrict__ src, const float* __restrict__ attr,
    const unsigned short* __restrict__ Xbf, const unsigned short* __restrict__ Bpk,
    const float* __restrict__ bias, void* __restrict__ outv, int N) {
  constexpr int RZ = K2 * 64;
  constexpr int R = (K2 + 1) * 64;     // 640 (K=3) / 1664 (K=5)
  constexpr int AS = R + 8;            // LDS row stride (shorts)
  constexpr int NKC = R / 32;          // 20 / 52
  __shared__ unsigned short As[16 * AS];
  __shared__ float4 sMeta[4][16];
  const int t = threadIdx.x, w = t >> 6, lane = t & 63;
  const int nodeBase = blockIdx.x * 16;

  const int col = lane & 31, half = lane >> 5;
  const int mi0 = (col < K2) ? (col % K) : -3;
  const int mi1 = (col < K2) ? (col / K) : -3;

  // ---------- phase 1: zbuild 4 nodes per wave into LDS ----------
  for (int g = 0; g < 4; ++g) {
    const int row = w * 4 + g;
    const int node = nodeBase + row;
    if (node < N) {
      floatx16 d0, d1;
#pragma unroll
      for (int i = 0; i < 16; ++i) { d0[i] = 0.f; d1[i] = 0.f; }

      const int beg = row_start[node], end = row_start[node + 1];
      for (int c0 = beg; c0 < end; c0 += 16) {
        const int m = min(16, end - c0);
        if (lane < 16) {
          float f0 = 0.f, f1 = 0.f;
          int lpack = 0x7F7F, off = 0;
          if (lane < m) {
            int e = eidx[c0 + lane];
            float2 a = *(const float2*)&attr[2 * e];
            int s = src[e];
            float u = a.x * (float)(K - 1);
            float v = a.y * (float)(K - 1);
            int l0 = min((int)u, K - 2);   // exact clip-equivalent
            int l1 = min((int)v, K - 2);
            f0 = u - (float)l0;
            f1 = v - (float)l1;
            lpack = l0 | (l1 << 8);
            off = s * 64;
          }
          sMeta[w][lane] = make_float4(f0, f1, __builtin_bit_cast(float, lpack),
                                       __builtin_bit_cast(float, off));
        }
        // same-wave LDS write->read (lockstep; compiler inserts lgkmcnt)
        short8 A, Blo, Bhi;
#pragma unroll
        for (int j = 0; j < 8; ++j) {
          float4 md = sMeta[w][half * 8 + j];
          int lp = __builtin_bit_cast(int, md.z);
          int off = __builtin_bit_cast(int, md.w);
          int l0 = lp & 0xFF, l1 = (lp >> 8) & 0xFF;
          float su = (mi0 == l0) ? (1.f - md.x) : ((mi0 == l0 + 1) ? md.x : 0.f);
          float sv = (mi1 == l1) ? (1.f - md.y) : ((mi1 == l1 + 1) ? md.y : 0.f);
          A[j] = (short)f2bf(su * sv);
          Blo[j] = (short)Xbf[off + col];
          Bhi[j] = (short)Xbf[off + 32 + col];
        }
        d0 = __builtin_amdgcn_mfma_f32_32x32x16_bf16(A, Blo, d0, 0, 0, 0);
        d1 = __builtin_amdgcn_mfma_f32_32x32x16_bf16(A, Bhi, d1, 0, 0, 0);
      }

      const float inv = 1.f / (float)max(end - beg, 1);
#pragma unroll
      for (int reg = 0; reg < 16; ++reg) {
        int r = (reg & 3) + 8 * (reg >> 2) + 4 * half;
        if (r < K2) {
          As[row * AS + r * 64 + col] = f2bf(d0[reg] * inv);
          As[row * AS + r * 64 + 32 + col] = f2bf(d1[reg] * inv);
        }
      }
      As[row * AS + RZ + lane] = Xbf[(size_t)node * 64 + lane];  // root row
    } else {
      for (int i = lane; i < R; i += 64) As[row * AS + i] = 0;
    }
  }
  __syncthreads();

  // ---------- phase 2: 16 x R x 64 GEMM + bias + ELU ----------
  const int mrow = lane & 15, q = lane >> 4;
  floatx4 acc = {0.f, 0.f, 0.f, 0.f};
  for (int kc = 0; kc < NKC; ++kc) {
    short8 a = *(const short8*)&As[mrow * AS + kc * 32 + q * 8];
    short8 b = *(const short8*)&Bpk[(((size_t)kc * 4 + w) * 64 + lane) * 8];
    acc = __builtin_amdgcn_mfma_f32_16x16x32_bf16(a, b, acc, 0, 0, 0);
  }

  // D layout: o_local = lane&15 (col), node_local = q*4+reg (row)
  const int o = w * 16 + mrow;
  const float bv = bias[o];
#pragma unroll
  for (int reg = 0; reg < 4; ++reg) {
    int node = nodeBase + q * 4 + reg;
    if (node < N) {
      float v = acc[reg] + bv;
      v = v > 0.f ? v : (expf(v) - 1.f);
      if (OUTBF)
        ((unsigned short*)outv)[(size_t)node * 64 + o] = f2bf(v);
      else
        ((float*)outv)[(size_t)node * 64 + o] = v;
    }
  }
}

// ---------------------------------------------------------------------
// dense layer (fp32 VALU): out = act(X@Wm + b); ACT 1=ReLU
// ---------------------------------------------------------------------
template <int ACT>
__global__ __launch_bounds__(256) void node_dense_kernel(
    const float* __restrict__ X, const float* __restrict__ Wm,
    const float* __restrict__ bias, float* __restrict__ out, int N) {
  __shared__ float Ws[64 * 64];
  __shared__ float XsT[64 * 132];
  const int t = threadIdx.x;
  const int n0 = blockIdx.x * 128;

  for (int i = t; i < 1024; i += 256)
    ((float4*)Ws)[i] = ((const float4*)Wm)[i];
  for (int i = t; i < 8192; i += 256) {
    int nl = i >> 6, d = i & 63;
    int n = n0 + nl;
    XsT[d * 132 + nl] = (n < N) ? X[(size_t)n * 64 + d] : 0.f;
  }
  __syncthreads();

  const int o = t & 63, ng = t >> 6;
  float acc[32];
#pragma unroll
  for (int j = 0; j < 32; ++j) acc[j] = 0.f;

  for (int d = 0; d < 64; ++d) {
    float w = Ws[d * 64 + o];
    const float4* xp = (const float4*)&XsT[d * 132 + ng * 32];
#pragma unroll
    for (int j4 = 0; j4 < 8; ++j4) {
      float4 xv = xp[j4];
      acc[j4 * 4 + 0] += xv.x * w;
      acc[j4 * 4 + 1] += xv.y * w;
      acc[j4 * 4 + 2] += xv.z * w;
      acc[j4 * 4 + 3] += xv.w * w;
    }
  }

  float b = bias[o];
#pragma unroll
  for (int j = 0; j < 32; ++j) {
    int n = n0 + ng * 32 + j;
    if (n >= N) continue;
    float v = acc[j] + b;
    if (ACT == 0) v = v > 0.f ? v : (expf(v) - 1.f);
    else          v = v > 0.f ? v : 0.f;
    out[(size_t)n * 64 + o] = v;
  }
}

// ---------------------------------------------------------------------
// final projection D=64 -> C=8 with ReLU
// ---------------------------------------------------------------------
__global__ __launch_bounds__(256) void mlp2_kernel(
    const float* __restrict__ X, const float* __restrict__ W,
    const float* __restrict__ bias, float* __restrict__ out, int N) {
  __shared__ float Ws[512];
  __shared__ float bs[8];
  __shared__ float Xs[32 * 64];
  int t = threadIdx.x;
  int n0 = blockIdx.x * 32;
  if (t < 8) bs[t] = bias[t];
  for (int i = t; i < 512; i += 256) Ws[i] = W[i];
  for (int i = t; i < 512; i += 256) {
    int n = n0 + (i >> 4);
    ((float4*)Xs)[i] = (n < N) ? ((const float4*)(X + (size_t)n * 64))[i & 15]
                               : make_float4(0.f, 0.f, 0.f, 0.f);
  }
  __syncthreads();
  int c = t & 7, nl = t >> 3;
  float acc = bs[c];
  for (int d = 0; d < 64; ++d) acc += Xs[nl * 64 + d] * Ws[d * 8 + c];
  int n = n0 + nl;
  if (n < N) out[(size_t)n * 8 + c] = acc > 0.f ? acc : 0.f;
}

// ---------------------------------------------------------------------
extern "C" void kernel_launch(void* const* d_in, const int* in_sizes, int n_in,
                              void* d_out, int out_size, void* d_ws, size_t ws_size,
                              hipStream_t stream) {
  const float* x     = (const float*)d_in[0];
  const int*   ei    = (const int*)d_in[1];
  const float* attr  = (const float*)d_in[2];
  const float* W1    = (const float*)d_in[3];
  const float* root1 = (const float*)d_in[4];
  const float* b1    = (const float*)d_in[5];
  const float* W2    = (const float*)d_in[6];
  const float* root2 = (const float*)d_in[7];
  const float* b2    = (const float*)d_in[8];
  const float* m1w   = (const float*)d_in[9];
  const float* m1b   = (const float*)d_in[10];
  const float* m2w   = (const float*)d_in[11];
  const float* m2b   = (const float*)d_in[12];

  const int N  = in_sizes[0] / 64;
  const int nE = in_sizes[1] / 2;
  const int* src  = ei;
  const int* dstv = ei + nE;
  float* out = (float*)d_out;

  // workspace layout
  float* h2 = (float*)d_ws;                 // N*64 fp32
  float* t1 = h2 + (size_t)N * 64;          // N*64 fp32
  int* deg       = (int*)(t1 + (size_t)N * 64);
  int* row_start = deg + N;
  int* cursor    = row_start + (N + 1);
  int* eidx      = cursor + N;
  int* partial   = eidx + nE;               // 256
  char* pbase = (char*)(partial + 256);
  pbase = (char*)(((uintptr_t)pbase + 15) & ~(uintptr_t)15);
  unsigned short* Xbf  = (unsigned short*)pbase;      // N*64 bf16
  unsigned short* h1bf = Xbf + (size_t)N * 64;        // N*64 bf16
  unsigned short* Bpk1 = h1bf + (size_t)N * 64;       // 64 * 640
  unsigned short* Bpk2 = Bpk1 + 64 * 640;             // 64 * 1664

  dim3 blk(256);
  int nbN  = (N + 255) / 256;
  int nbE  = (nE + 255) / 256;
  int nbF  = (N + 15) / 16;
  int nb128 = (N + 127) / 128;

  // ----- CSR build (graph identical both layers) -----
  zero_int_kernel<<<nbN, blk, 0, stream>>>(deg, N);
  hist_kernel<<<nbE, blk, 0, stream>>>(dstv, deg, nE);
  blocksum_kernel<<<nbN, blk, 0, stream>>>(deg, partial, N);
  scanpartials_kernel<<<1, blk, 0, stream>>>(partial, nbN);
  blockscan_kernel<<<nbN, blk, 0, stream>>>(deg, partial, row_start, cursor, N, nE);
  scatter_kernel<<<nbE, blk, 0, stream>>>(dstv, cursor, eidx, nE);

  // ----- weight / input prep -----
  pack_b_kernel<<<(64 * 640 + 255) / 256, blk, 0, stream>>>(W1, root1, Bpk1, 9);
  pack_b_kernel<<<(64 * 1664 + 255) / 256, blk, 0, stream>>>(W2, root2, Bpk2, 25);
  cvt_x_kernel<<<(N * 64 + 255) / 256, blk, 0, stream>>>(x, Xbf, N * 64);

  // ----- layer 1 (K=3, K2=9): fused zbuild+GEMM, bf16 out -----
  spline_layer_kernel<3, 9, 1><<<nbF, blk, 0, stream>>>(
      eidx, row_start, src, attr, Xbf, Bpk1, b1, h1bf, N);

  // ----- layer 2 (K=5, K2=25): fused zbuild+GEMM, fp32 out -----
  spline_layer_kernel<5, 25, 0><<<nbF, blk, 0, stream>>>(
      eidx, row_start, src, attr, h1bf, Bpk2, b2, h2, N);

  // ----- MLP head -----
  node_dense_kernel<1><<<nb128, blk, 0, stream>>>(h2, m1w, m1b, t1, N);
  mlp2_kernel<<<(N + 31) / 32, blk, 0, stream>>>(t1, m2w, m2b, out, N);
}

// Round 14
// 370.873 us; speedup vs baseline: 1.2368x; 1.1274x over previous
//
#include <hip/hip_runtime.h>
#include <hip/hip_bf16.h>

typedef __attribute__((ext_vector_type(8))) short short8;
typedef __attribute__((ext_vector_type(4))) float floatx4;
typedef __attribute__((ext_vector_type(16))) float floatx16;

__device__ __forceinline__ unsigned short f2bf(float x) {
  __hip_bfloat16 h = __float2bfloat16(x);
  return __builtin_bit_cast(unsigned short, h);
}

// ---------------------------------------------------------------------
// X (fp32) -> bf16 copy
// ---------------------------------------------------------------------
__global__ __launch_bounds__(256) void cvt_x_kernel(
    const float* __restrict__ X, unsigned short* __restrict__ Xbf, int n) {
  int i = blockIdx.x * 256 + threadIdx.x;
  if (i < n) Xbf[i] = f2bf(X[i]);
}

// ---------------------------------------------------------------------
// Pack extended weights [W | root] into MFMA B-fragment order:
// Bpk[(((kc*4)+wv)*64 + lane)*8 + j] = Wext[wv*16 + (lane&15)]
//                                          [kc*32 + ((lane>>4)&3)*8 + j]
// ---------------------------------------------------------------------
__global__ __launch_bounds__(256) void pack_b_kernel(
    const float* __restrict__ W, const float* __restrict__ root,
    unsigned short* __restrict__ Bpk, int K2) {
  int R = (K2 + 1) * 64;
  int total = 64 * R;
  int i = blockIdx.x * 256 + threadIdx.x;
  if (i >= total) return;
  int j = i & 7;
  int lane = (i >> 3) & 63;
  int rest = i >> 9;            // kc*4 + wv
  int wv = rest & 3, kc = rest >> 2;
  int o = wv * 16 + (lane & 15);
  int r = kc * 32 + ((lane >> 4) & 3) * 8 + j;
  int k = r >> 6, d = r & 63;
  float v = (k < K2) ? W[(k << 12) + (d << 6) + o] : root[(d << 6) + o];
  Bpk[i] = f2bf(v);
}

// ---------------------------------------------------------------------
// CSR build: histogram -> scan -> cursor scatter (emits packed edge recs)
// ---------------------------------------------------------------------
__global__ __launch_bounds__(256) void zero_int_kernel(int* __restrict__ p, int n) {
  int i = blockIdx.x * 256 + threadIdx.x;
  if (i < n) p[i] = 0;
}

__global__ __launch_bounds__(256) void hist_kernel(
    const int* __restrict__ dst, int* __restrict__ deg, int nE) {
  int e = blockIdx.x * 256 + threadIdx.x;
  if (e < nE) atomicAdd(&deg[dst[e]], 1);
}

__global__ __launch_bounds__(256) void blocksum_kernel(
    const int* __restrict__ deg, int* __restrict__ partial, int N) {
  __shared__ int s[256];
  int t = threadIdx.x, i = blockIdx.x * 256 + t;
  s[t] = (i < N) ? deg[i] : 0;
  __syncthreads();
  for (int off = 128; off > 0; off >>= 1) {
    if (t < off) s[t] += s[t + off];
    __syncthreads();
  }
  if (t == 0) partial[blockIdx.x] = s[0];
}

__global__ __launch_bounds__(256) void scanpartials_kernel(
    int* __restrict__ partial, int nb) {
  __shared__ int s[256];
  int t = threadIdx.x;
  int v = (t < nb) ? partial[t] : 0;
  s[t] = v;
  __syncthreads();
  for (int off = 1; off < 256; off <<= 1) {
    int x = (t >= off) ? s[t - off] : 0;
    __syncthreads();
    s[t] += x;
    __syncthreads();
  }
  if (t < nb) partial[t] = s[t] - v;
}

__global__ __launch_bounds__(256) void blockscan_kernel(
    const int* __restrict__ deg, const int* __restrict__ partial,
    int* __restrict__ row_start, int* __restrict__ cursor, int N, int nE) {
  __shared__ int s[256];
  int t = threadIdx.x, i = blockIdx.x * 256 + t;
  int v = (i < N) ? deg[i] : 0;
  s[t] = v;
  __syncthreads();
  for (int off = 1; off < 256; off <<= 1) {
    int x = (t >= off) ? s[t - off] : 0;
    __syncthreads();
    s[t] += x;
    __syncthreads();
  }
  if (i < N) {
    int excl = s[t] - v + partial[blockIdx.x];
    row_start[i] = excl;
    cursor[i] = excl;
  }
  if (i == 0) row_start[N] = nE;
}

// Record: x=f0, y=f1, z=bit(l0|l1<<8), w=bit(src*64). One per edge per K.
__global__ __launch_bounds__(256) void scatter_rec_kernel(
    const int* __restrict__ dst, const int* __restrict__ src,
    const float* __restrict__ attr, int* __restrict__ cursor,
    float4* __restrict__ rec3, float4* __restrict__ rec5, int nE) {
  int e = blockIdx.x * 256 + threadIdx.x;
  if (e >= nE) return;
  int pos = atomicAdd(&cursor[dst[e]], 1);
  float2 a = *(const float2*)&attr[2 * e];
  int off = src[e] * 64;
  {
    float u = a.x * 2.f, v = a.y * 2.f;
    int l0 = min((int)u, 1), l1 = min((int)v, 1);
    rec3[pos] = make_float4(u - (float)l0, v - (float)l1,
                            __builtin_bit_cast(float, l0 | (l1 << 8)),
                            __builtin_bit_cast(float, off));
  }
  {
    float u = a.x * 4.f, v = a.y * 4.f;
    int l0 = min((int)u, 3), l1 = min((int)v, 3);
    rec5[pos] = make_float4(u - (float)l0, v - (float)l1,
                            __builtin_bit_cast(float, l0 | (l1 << 8)),
                            __builtin_bit_cast(float, off));
  }
}

// ---------------------------------------------------------------------
// FUSED spline layer: block = 4 waves = 16 dst nodes.
// Phase 1 (per wave, 4 nodes): MFMA bucket-aggregate (32x32x16) reading
//   packed 16B edge records (one broadcast load/edge, no meta chain, no
//   sMeta LDS) and gathering bf16 x-rows; scaled Z + root row -> LDS.
// Phase 2: out[16 x 64] = ELU( A[16 x R] @ B + b ), B pre-packed.
// LDS = As only (53.5 KB @ K=5) -> 3 blocks/CU (was 2 with sMeta).
// ---------------------------------------------------------------------
template <int K, int K2, int OUTBF>
__global__ __launch_bounds__(256) void spline_layer_kernel(
    const float4* __restrict__ rec, const int* __restrict__ row_start,
    const unsigned short* __restrict__ Xbf, const unsigned short* __restrict__ Bpk,
    const float* __restrict__ bias, void* __restrict__ outv, int N) {
  constexpr int RZ = K2 * 64;
  constexpr int R = (K2 + 1) * 64;     // 640 (K=3) / 1664 (K=5)
  constexpr int AS = R + 8;            // LDS row stride (shorts), 2-way banks
  constexpr int NKC = R / 32;          // 20 / 52
  __shared__ unsigned short As[16 * AS];
  const int t = threadIdx.x, w = t >> 6, lane = t & 63;
  const int nodeBase = blockIdx.x * 16;

  const int col = lane & 31, half = lane >> 5;
  const int mi0 = (col < K2) ? (col % K) : -3;
  const int mi1 = (col < K2) ? (col / K) : -3;

  // ---------- phase 1: zbuild 4 nodes per wave into LDS ----------
  for (int g = 0; g < 4; ++g) {
    const int row = w * 4 + g;
    const int node = nodeBase + row;
    if (node < N) {
      floatx16 d0, d1;
#pragma unroll
      for (int i = 0; i < 16; ++i) { d0[i] = 0.f; d1[i] = 0.f; }

      const int beg = row_start[node], end = row_start[node + 1];
      for (int c0 = beg; c0 < end; c0 += 16) {
        const int m = min(16, end - c0);
        // 8 independent broadcast record loads (uniform within each half)
        float4 rj[8];
#pragma unroll
        for (int j = 0; j < 8; ++j) {
          int idx = half * 8 + j;
          rj[j] = rec[c0 + min(idx, m - 1)];
          if (idx >= m) rj[j].z = __builtin_bit_cast(float, 0x7F7F);
        }
        short8 A, Blo, Bhi;
#pragma unroll
        for (int j = 0; j < 8; ++j) {
          int lp = __builtin_bit_cast(int, rj[j].z);
          int off = __builtin_bit_cast(int, rj[j].w);
          int l0 = lp & 0xFF, l1 = (lp >> 8) & 0xFF;
          float su = (mi0 == l0) ? (1.f - rj[j].x) : ((mi0 == l0 + 1) ? rj[j].x : 0.f);
          float sv = (mi1 == l1) ? (1.f - rj[j].y) : ((mi1 == l1 + 1) ? rj[j].y : 0.f);
          A[j] = (short)f2bf(su * sv);
          Blo[j] = (short)Xbf[off + col];
          Bhi[j] = (short)Xbf[off + 32 + col];
        }
        d0 = __builtin_amdgcn_mfma_f32_32x32x16_bf16(A, Blo, d0, 0, 0, 0);
        d1 = __builtin_amdgcn_mfma_f32_32x32x16_bf16(A, Bhi, d1, 0, 0, 0);
      }

      const float inv = 1.f / (float)max(end - beg, 1);
#pragma unroll
      for (int reg = 0; reg < 16; ++reg) {
        int r = (reg & 3) + 8 * (reg >> 2) + 4 * half;
        if (r < K2) {
          As[row * AS + r * 64 + col] = f2bf(d0[reg] * inv);
          As[row * AS + r * 64 + 32 + col] = f2bf(d1[reg] * inv);
        }
      }
      As[row * AS + RZ + lane] = Xbf[(size_t)node * 64 + lane];  // root row
    } else {
      for (int i = lane; i < R; i += 64) As[row * AS + i] = 0;
    }
  }
  __syncthreads();

  // ---------- phase 2: 16 x R x 64 GEMM + bias + ELU ----------
  const int mrow = lane & 15, q = lane >> 4;
  floatx4 acc = {0.f, 0.f, 0.f, 0.f};
  for (int kc = 0; kc < NKC; ++kc) {
    short8 a = *(const short8*)&As[mrow * AS + kc * 32 + q * 8];
    short8 b = *(const short8*)&Bpk[(((size_t)kc * 4 + w) * 64 + lane) * 8];
    acc = __builtin_amdgcn_mfma_f32_16x16x32_bf16(a, b, acc, 0, 0, 0);
  }

  // D layout: o_local = lane&15 (col), node_local = q*4+reg (row)
  const int o = w * 16 + mrow;
  const float bv = bias[o];
#pragma unroll
  for (int reg = 0; reg < 4; ++reg) {
    int node = nodeBase + q * 4 + reg;
    if (node < N) {
      float v = acc[reg] + bv;
      v = v > 0.f ? v : (expf(v) - 1.f);
      if (OUTBF)
        ((unsigned short*)outv)[(size_t)node * 64 + o] = f2bf(v);
      else
        ((float*)outv)[(size_t)node * 64 + o] = v;
    }
  }
}

// ---------------------------------------------------------------------
// dense layer (fp32 VALU): out = act(X@Wm + b); ACT 1=ReLU
// ---------------------------------------------------------------------
template <int ACT>
__global__ __launch_bounds__(256) void node_dense_kernel(
    const float* __restrict__ X, const float* __restrict__ Wm,
    const float* __restrict__ bias, float* __restrict__ out, int N) {
  __shared__ float Ws[64 * 64];
  __shared__ float XsT[64 * 132];
  const int t = threadIdx.x;
  const int n0 = blockIdx.x * 128;

  for (int i = t; i < 1024; i += 256)
    ((float4*)Ws)[i] = ((const float4*)Wm)[i];
  for (int i = t; i < 8192; i += 256) {
    int nl = i >> 6, d = i & 63;
    int n = n0 + nl;
    XsT[d * 132 + nl] = (n < N) ? X[(size_t)n * 64 + d] : 0.f;
  }
  __syncthreads();

  const int o = t & 63, ng = t >> 6;
  float acc[32];
#pragma unroll
  for (int j = 0; j < 32; ++j) acc[j] = 0.f;

  for (int d = 0; d < 64; ++d) {
    float w = Ws[d * 64 + o];
    const float4* xp = (const float4*)&XsT[d * 132 + ng * 32];
#pragma unroll
    for (int j4 = 0; j4 < 8; ++j4) {
      float4 xv = xp[j4];
      acc[j4 * 4 + 0] += xv.x * w;
      acc[j4 * 4 + 1] += xv.y * w;
      acc[j4 * 4 + 2] += xv.z * w;
      acc[j4 * 4 + 3] += xv.w * w;
    }
  }

  float b = bias[o];
#pragma unroll
  for (int j = 0; j < 32; ++j) {
    int n = n0 + ng * 32 + j;
    if (n >= N) continue;
    float v = acc[j] + b;
    if (ACT == 0) v = v > 0.f ? v : (expf(v) - 1.f);
    else          v = v > 0.f ? v : 0.f;
    out[(size_t)n * 64 + o] = v;
  }
}

// ---------------------------------------------------------------------
// final projection D=64 -> C=8 with ReLU
// ---------------------------------------------------------------------
__global__ __launch_bounds__(256) void mlp2_kernel(
    const float* __restrict__ X, const float* __restrict__ W,
    const float* __restrict__ bias, float* __restrict__ out, int N) {
  __shared__ float Ws[512];
  __shared__ float bs[8];
  __shared__ float Xs[32 * 64];
  int t = threadIdx.x;
  int n0 = blockIdx.x * 32;
  if (t < 8) bs[t] = bias[t];
  for (int i = t; i < 512; i += 256) Ws[i] = W[i];
  for (int i = t; i < 512; i += 256) {
    int n = n0 + (i >> 4);
    ((float4*)Xs)[i] = (n < N) ? ((const float4*)(X + (size_t)n * 64))[i & 15]
                               : make_float4(0.f, 0.f, 0.f, 0.f);
  }
  __syncthreads();
  int c = t & 7, nl = t >> 3;
  float acc = bs[c];
  for (int d = 0; d < 64; ++d) acc += Xs[nl * 64 + d] * Ws[d * 8 + c];
  int n = n0 + nl;
  if (n < N) out[(size_t)n * 8 + c] = acc > 0.f ? acc : 0.f;
}

// ---------------------------------------------------------------------
extern "C" void kernel_launch(void* const* d_in, const int* in_sizes, int n_in,
                              void* d_out, int out_size, void* d_ws, size_t ws_size,
                              hipStream_t stream) {
  const float* x     = (const float*)d_in[0];
  const int*   ei    = (const int*)d_in[1];
  const float* attr  = (const float*)d_in[2];
  const float* W1    = (const float*)d_in[3];
  const float* root1 = (const float*)d_in[4];
  const float* b1    = (const float*)d_in[5];
  const float* W2    = (const float*)d_in[6];
  const float* root2 = (const float*)d_in[7];
  const float* b2    = (const float*)d_in[8];
  const float* m1w   = (const float*)d_in[9];
  const float* m1b   = (const float*)d_in[10];
  const float* m2w   = (const float*)d_in[11];
  const float* m2b   = (const float*)d_in[12];

  const int N  = in_sizes[0] / 64;
  const int nE = in_sizes[1] / 2;
  const int* src  = ei;
  const int* dstv = ei + nE;
  float* out = (float*)d_out;

  // workspace layout
  float* h2 = (float*)d_ws;                 // N*64 fp32
  float* t1 = h2 + (size_t)N * 64;          // N*64 fp32
  int* deg       = (int*)(t1 + (size_t)N * 64);
  int* row_start = deg + N;
  int* cursor    = row_start + (N + 1);
  int* partial   = cursor + N;              // 256
  char* pbase = (char*)(partial + 256);
  pbase = (char*)(((uintptr_t)pbase + 15) & ~(uintptr_t)15);
  float4* rec3 = (float4*)pbase;                      // nE * 16B
  float4* rec5 = rec3 + nE;                           // nE * 16B
  unsigned short* Xbf  = (unsigned short*)(rec5 + nE);  // N*64 bf16
  unsigned short* h1bf = Xbf + (size_t)N * 64;          // N*64 bf16
  unsigned short* Bpk1 = h1bf + (size_t)N * 64;         // 64 * 640
  unsigned short* Bpk2 = Bpk1 + 64 * 640;               // 64 * 1664

  dim3 blk(256);
  int nbN  = (N + 255) / 256;
  int nbE  = (nE + 255) / 256;
  int nbF  = (N + 15) / 16;
  int nb128 = (N + 127) / 128;

  // ----- CSR build (graph identical both layers) -----
  zero_int_kernel<<<nbN, blk, 0, stream>>>(deg, N);
  hist_kernel<<<nbE, blk, 0, stream>>>(dstv, deg, nE);
  blocksum_kernel<<<nbN, blk, 0, stream>>>(deg, partial, N);
  scanpartials_kernel<<<1, blk, 0, stream>>>(partial, nbN);
  blockscan_kernel<<<nbN, blk, 0, stream>>>(deg, partial, row_start, cursor, N, nE);
  scatter_rec_kernel<<<nbE, blk, 0, stream>>>(dstv, src, attr, cursor, rec3, rec5, nE);

  // ----- weight / input prep -----
  pack_b_kernel<<<(64 * 640 + 255) / 256, blk, 0, stream>>>(W1, root1, Bpk1, 9);
  pack_b_kernel<<<(64 * 1664 + 255) / 256, blk, 0, stream>>>(W2, root2, Bpk2, 25);
  cvt_x_kernel<<<(N * 64 + 255) / 256, blk, 0, stream>>>(x, Xbf, N * 64);

  // ----- layer 1 (K=3, K2=9): fused zbuild+GEMM, bf16 out -----
  spline_layer_kernel<3, 9, 1><<<nbF, blk, 0, stream>>>(
      rec3, row_start, Xbf, Bpk1, b1, h1bf, N);

  // ----- layer 2 (K=5, K2=25): fused zbuild+GEMM, fp32 out -----
  spline_layer_kernel<5, 25, 0><<<nbF, blk, 0, stream>>>(
      rec5, row_start, h1bf, Bpk2, b2, h2, N);

  // ----- MLP head -----
  node_dense_kernel<1><<<nb128, blk, 0, stream>>>(h2, m1w, m1b, t1, N);
  mlp2_kernel<<<(N + 31) / 32, blk, 0, stream>>>(t1, m2w, m2b, out, N);
}